// Round 7
// baseline (4707.082 us; speedup 1.0000x reference)
//
#include <hip/hip_runtime.h>
#include <hip/hip_cooperative_groups.h>
#include <cmath>

// Memory_76957224010242: 100-step Adam inference loop.
// G = W^T W, u = (x-c)@W once; per-iter s = r@G fused with Adam + loss.
// R6: persistent cooperative kernel — all 100 iters in ONE dispatch with
// grid.sync(); r/m/v/u/b live in registers; only bf16(r) is published per iter
// (ping-pong) for the next iteration's GEMM A-operand. Kills 100 launch gaps +
// 20 MB/iter of state reload that made R5's in-kernel pipelining irrelevant.

#define B_SZ 512
#define H_SZ 2048
#define D_SZ 4096
#define ITERS 100

typedef __attribute__((ext_vector_type(8))) short short8;
typedef __attribute__((ext_vector_type(4))) float f32x4;

__device__ __forceinline__ unsigned short f2bf(float f) {
    unsigned u = __float_as_uint(f);
    u = (u + 0x7fffu + ((u >> 16) & 1u)) >> 16;  // RNE
    return (unsigned short)u;
}

__device__ __forceinline__ void gload_lds16(const unsigned short* g, unsigned short* l) {
    __builtin_amdgcn_global_load_lds((const __attribute__((address_space(1))) void*)g,
                                     (__attribute__((address_space(3))) void*)l, 16, 0, 0);
}

// ---- W (D,H) f32 -> Wt (H,D) bf16 (transpose + cast) ----
__global__ __launch_bounds__(256) void k_transpose(const float* __restrict__ W,
                                                   unsigned short* __restrict__ Wt) {
    __shared__ unsigned short tile[64][72];
    const int d0 = blockIdx.x * 64, h0 = blockIdx.y * 64;
    const int t = threadIdx.x;
    const int lr = t >> 6, lc = t & 63;
#pragma unroll
    for (int rr = 0; rr < 16; ++rr) {
        const int dl = rr * 4 + lr;
        tile[dl][lc] = f2bf(W[(size_t)(d0 + dl) * H_SZ + h0 + lc]);
    }
    __syncthreads();
#pragma unroll
    for (int rr = 0; rr < 16; ++rr) {
        const int hl = rr * 4 + lr;
        Wt[(size_t)(h0 + hl) * D_SZ + d0 + lc] = tile[lc][hl];
    }
}

// ---- xc = (x - c) bf16, xc2[b] = sum_d (x-c)^2 ----
__global__ __launch_bounds__(256) void k_prepx(const float* __restrict__ x, const float* __restrict__ c,
                                               unsigned short* __restrict__ xcbf, float* __restrict__ xc2) {
    const int b = blockIdx.x, t = threadIdx.x;
    const float* xr = x + (size_t)b * D_SZ;
    unsigned short* orow = xcbf + (size_t)b * D_SZ;
    float acc = 0.f;
#pragma unroll
    for (int ch = 0; ch < 2; ++ch) {
        const int base = (ch * 256 + t) * 8;
        const float4 v0 = *(const float4*)(xr + base);
        const float4 v1 = *(const float4*)(xr + base + 4);
        const float4 c0 = *(const float4*)(c + base);
        const float4 c1 = *(const float4*)(c + base + 4);
        const float e0 = v0.x - c0.x, e1 = v0.y - c0.y, e2 = v0.z - c0.z, e3 = v0.w - c0.w;
        const float e4 = v1.x - c1.x, e5 = v1.y - c1.y, e6 = v1.z - c1.z, e7 = v1.w - c1.w;
        acc += e0 * e0 + e1 * e1 + e2 * e2 + e3 * e3 + e4 * e4 + e5 * e5 + e6 * e6 + e7 * e7;
        short8 ov;
        ov[0] = (short)f2bf(e0); ov[1] = (short)f2bf(e1); ov[2] = (short)f2bf(e2); ov[3] = (short)f2bf(e3);
        ov[4] = (short)f2bf(e4); ov[5] = (short)f2bf(e5); ov[6] = (short)f2bf(e6); ov[7] = (short)f2bf(e7);
        *(short8*)(orow + base) = ov;
    }
#pragma unroll
    for (int off = 32; off > 0; off >>= 1) acc += __shfl_down(acc, off);
    __shared__ float wred[4];
    if ((t & 63) == 0) wred[t >> 6] = acc;
    __syncthreads();
    if (t == 0) xc2[b] = wred[0] + wred[1] + wred[2] + wred[3];
}

// ---- rbfA = bf16(r0) ----
__global__ __launch_bounds__(256) void k_init(const float* __restrict__ r0,
                                              unsigned short* __restrict__ rbfA) {
    const size_t i = (size_t)blockIdx.x * 256 + threadIdx.x;
#pragma unroll
    for (int k = 0; k < 4; ++k) {
        const size_t idx = i + (size_t)k * 262144;
        rbfA[idx] = f2bf(r0[idx]);
    }
}

// ---- one-time TM x 64 tile bf16 MFMA GEMM (EPI 0: bf16 store; EPI 1: f32 store) ----
template <int TM, int EPI>
__global__ __launch_bounds__(256) void gemm64(
        const unsigned short* __restrict__ A, int lda,
        const unsigned short* __restrict__ Bt, int ldb, int K,
        unsigned short* __restrict__ Cb, float* __restrict__ Cf, int ldc) {
    __shared__ alignas(16) unsigned short Al[2][TM * 64];
    __shared__ alignas(16) unsigned short Bl[2][64 * 64];
    const int t = threadIdx.x, w = t >> 6, lane = t & 63;
    const int m0 = blockIdx.y * TM, n0 = blockIdx.x * 64;
    constexpr int NJ = (TM == 64) ? 2 : 1;
    const int row_base = (TM == 64) ? (w >> 1) * 32 : 0;
    const int col_base = (TM == 64) ? (w & 1) * 32 : w * 16;

    f32x4 acc[2][NJ] = {};

    auto stage = [&](int buf, int k0) {
#pragma unroll
        for (int h = 0; h < 2; ++h) {
            const int c = h * 256 + t;
            const int row = c >> 3, g = c & 7;
            const int gl = g ^ (row & 7);
            gload_lds16(Bt + (size_t)(n0 + row) * ldb + k0 + gl * 8, &Bl[buf][(h * 256 + w * 64) * 8]);
        }
        if constexpr (TM == 64) {
#pragma unroll
            for (int h = 0; h < 2; ++h) {
                const int c = h * 256 + t;
                const int row = c >> 3, g = c & 7;
                const int gl = g ^ (row & 7);
                gload_lds16(A + (size_t)(m0 + row) * lda + k0 + gl * 8, &Al[buf][(h * 256 + w * 64) * 8]);
            }
        } else {
            const int row = t >> 3, g = t & 7;
            const int gl = g ^ (row & 7);
            gload_lds16(A + (size_t)(m0 + row) * lda + k0 + gl * 8, &Al[buf][(w * 64) * 8]);
        }
    };

    stage(0, 0);
    const int nK = K >> 6;
    for (int kt = 0; kt < nK; ++kt) {
        __syncthreads();
        const int cur = kt & 1;
        if (kt + 1 < nK) stage(cur ^ 1, (kt + 1) << 6);
        const unsigned short* a_base = Al[cur];
        const unsigned short* b_base = Bl[cur];
#pragma unroll
        for (int kh = 0; kh < 2; ++kh) {
            short8 av[2], bv[NJ];
#pragma unroll
            for (int i = 0; i < 2; ++i) {
                const int row = row_base + i * 16 + (lane & 15);
                const int g = (kh * 4 + (lane >> 4)) ^ (row & 7);
                av[i] = *(const short8*)(a_base + row * 64 + g * 8);
            }
#pragma unroll
            for (int j = 0; j < NJ; ++j) {
                const int row = col_base + j * 16 + (lane & 15);
                const int g = (kh * 4 + (lane >> 4)) ^ (row & 7);
                bv[j] = *(const short8*)(b_base + row * 64 + g * 8);
            }
#pragma unroll
            for (int i = 0; i < 2; ++i)
#pragma unroll
                for (int j = 0; j < NJ; ++j)
                    acc[i][j] = __builtin_amdgcn_mfma_f32_16x16x32_bf16(av[i], bv[j], acc[i][j], 0, 0, 0);
        }
    }

#pragma unroll
    for (int i = 0; i < 2; ++i)
#pragma unroll
        for (int j = 0; j < NJ; ++j) {
            const int col = n0 + col_base + j * 16 + (lane & 15);
            const int row0 = m0 + row_base + i * 16 + ((lane >> 4) << 2);
#pragma unroll
            for (int q = 0; q < 4; ++q) {
                if constexpr (EPI == 0) Cb[(size_t)(row0 + q) * ldc + col] = f2bf(acc[i][j][q]);
                else Cf[(size_t)(row0 + q) * ldc + col] = acc[i][j][q];
            }
        }
}

// ---- persistent cooperative kernel: 100 Adam iterations in one dispatch.
// 256 blocks x 512 threads (1/CU, 8 waves). Block tile 64m x 64n; wave 32m x 16n.
// r/m/v/u/b in registers; bf16(r) published per iter (ping-pong) + grid.sync().
__global__ __launch_bounds__(512, 2) void k_persist(
        const float* __restrict__ r0,
        unsigned short* __restrict__ rbfA,
        unsigned short* __restrict__ rbfB,
        const unsigned short* __restrict__ G,
        const float* __restrict__ ubuf,
        const float* __restrict__ bvec,
        const float* __restrict__ xc2,
        float* __restrict__ lossPart,
        float* __restrict__ out) {
    cooperative_groups::grid_group grid = cooperative_groups::this_grid();
    __shared__ alignas(16) unsigned short Al[4][64 * 64];  // 4-buffer, 3-deep prefetch
    __shared__ alignas(16) unsigned short Bl[4][64 * 64];
    __shared__ float wred[8];
    const int t = threadIdx.x, w = t >> 6, lane = t & 63;
    const int bid = blockIdx.x;
    const int m0 = (bid >> 5) * 64;      // 8 m-tiles
    const int n0 = (bid & 31) * 64;      // 32 n-tiles; bid%8=XCD -> 4 static G panels/XCD (1 MB, L2-hot)
    const int row_base = (w >> 2) * 32;  // wave tile: 32m x 16n
    const int col_base = (w & 3) * 16;
    const int col = n0 + col_base + (lane & 15);

    const int srow = t >> 3;                       // staging: row per thread
    const int sgl = (t & 7) ^ (srow & 7);          // source-side XOR swizzle (Guideline 21)

    // persistent per-thread state (8 outputs: 2 frags x 4)
    float rs[8], ms[8], vs[8], us[8];
    const float bval = bvec[col];
#pragma unroll
    for (int i = 0; i < 2; ++i)
#pragma unroll
        for (int q = 0; q < 4; ++q) {
            const int e = i * 4 + q;
            const size_t idx = (size_t)(m0 + row_base + i * 16 + ((lane >> 4) << 2) + q) * H_SZ + col;
            rs[e] = r0[idx];
            us[e] = ubuf[idx];
            ms[e] = 0.f; vs[e] = 0.f;
        }

    float p1 = 1.f, p2 = 1.f;
    for (int it = 0; it < ITERS; ++it) {
        p1 *= 0.9f; p2 *= 0.999f;
        const float inv1 = 1.f / (1.f - p1);
        const float inv2 = 1.f / (1.f - p2);
        const unsigned short* Ain = (it & 1) ? rbfB : rbfA;
        unsigned short* Aout = (it & 1) ? rbfA : rbfB;

        f32x4 acc[2] = {};
        auto stage = [&](int buf, int kc) {  // 2 loads/thread (1 A + 1 G), uniform
            const int k0 = kc * 64;
            gload_lds16(Ain + (size_t)(m0 + srow) * H_SZ + k0 + sgl * 8, &Al[buf][t * 8]);
            gload_lds16(G + (size_t)(n0 + srow) * H_SZ + k0 + sgl * 8, &Bl[buf][t * 8]);
        };
        stage(0, 0); stage(1, 1); stage(2, 2);
        for (int kt = 0; kt < 32; ++kt) {
            // counted vmcnt: 3 stages in flight = 6 loads; oldest stage done at <=4.
            if (kt < 30)       asm volatile("s_waitcnt vmcnt(4)" ::: "memory");
            else if (kt == 30) asm volatile("s_waitcnt vmcnt(2)" ::: "memory");
            else               asm volatile("s_waitcnt vmcnt(0)" ::: "memory");
            __builtin_amdgcn_s_barrier();
            __builtin_amdgcn_sched_barrier(0);  // pin ds_reads below the barrier
            if (kt + 3 < 32) stage((kt + 3) & 3, kt + 3);
            const unsigned short* a_base = Al[kt & 3];
            const unsigned short* b_base = Bl[kt & 3];
#pragma unroll
            for (int kh = 0; kh < 2; ++kh) {
                short8 av[2], bv;
#pragma unroll
                for (int i = 0; i < 2; ++i) {
                    const int row = row_base + i * 16 + (lane & 15);
                    const int g = (kh * 4 + (lane >> 4)) ^ (row & 7);
                    av[i] = *(const short8*)(a_base + row * 64 + g * 8);
                }
                {
                    const int row = col_base + (lane & 15);
                    const int g = (kh * 4 + (lane >> 4)) ^ (row & 7);
                    bv = *(const short8*)(b_base + row * 64 + g * 8);
                }
#pragma unroll
                for (int i = 0; i < 2; ++i)
                    acc[i] = __builtin_amdgcn_mfma_f32_16x16x32_bf16(av[i], bv, acc[i], 0, 0, 0);
            }
        }

        // fused Adam + loss, all state in registers
        float lpart = 0.f;
#pragma unroll
        for (int i = 0; i < 2; ++i)
#pragma unroll
            for (int q = 0; q < 4; ++q) {
                const int e = i * 4 + q;
                const size_t idx = (size_t)(m0 + row_base + i * 16 + ((lane >> 4) << 2) + q) * H_SZ + col;
                const float s = acc[i][q];
                const float rold = rs[e];
                const float ue = us[e];
                const float g = (2.0f / B_SZ) * (rold - bval - ue + s);
                lpart += (rold - bval) * (rold - bval) + rold * (s - 2.0f * ue);
                ms[e] = 0.9f * ms[e] + 0.1f * g;
                vs[e] = 0.999f * vs[e] + 0.001f * (g * g);
                const float rn = rold - 0.01f * (ms[e] * inv1) / (sqrtf(vs[e] * inv2) + 1e-8f);
                rs[e] = rn;
                if (it + 1 < ITERS) Aout[idx] = f2bf(rn);
                else out[idx] = rn;  // final iteration: write f32 r straight to output
            }
#pragma unroll
        for (int off = 32; off > 0; off >>= 1) lpart += __shfl_down(lpart, off);
        if (lane == 0) wred[w] = lpart;
        __syncthreads();
        if (t == 0) {
            float sum = 0.f;
#pragma unroll
            for (int k = 0; k < 8; ++k) sum += wred[k];
            lossPart[it * 256 + bid] = sum;
        }
        grid.sync();  // publishes Aout (+ lossPart) grid-wide; guards ping-pong reuse
    }

    // finalize losses in-kernel: block 'bid'<100 reduces iteration bid's 256 partials
    float p = 0.f;
    if (bid < ITERS && t < 256) p = lossPart[bid * 256 + t] + xc2[t] + xc2[t + 256];
#pragma unroll
    for (int off = 32; off > 0; off >>= 1) p += __shfl_down(p, off);
    __shared__ float wred2[8];
    if (lane == 0) wred2[w] = p;
    __syncthreads();
    if (t == 0 && bid < ITERS) {
        float sum = 0.f;
#pragma unroll
        for (int k = 0; k < 8; ++k) sum += wred2[k];
        out[(size_t)B_SZ * H_SZ + bid] = sum * (1.0f / B_SZ);
    }
}

extern "C" void kernel_launch(void* const* d_in, const int* in_sizes, int n_in,
                              void* d_out, int out_size, void* d_ws, size_t ws_size,
                              hipStream_t stream) {
    const float* x = (const float*)d_in[0];
    const float* W = (const float*)d_in[1];
    const float* cvec = (const float*)d_in[2];
    const float* bvec = (const float*)d_in[3];
    const float* r0 = (const float*)d_in[4];
    float* out = (float*)d_out;
    char* ws = (char*)d_ws;

    unsigned short* Wt = (unsigned short*)(ws);              // 16 MB   (H x D bf16)
    unsigned short* Gbf = (unsigned short*)(ws + 16777216);  // 8 MB    (H x H bf16)
    unsigned short* xcbf = (unsigned short*)(ws + 25165824); // 4 MB    (B x D bf16)
    float* u = (float*)(ws + 29360128);                      // 4 MB    (B x H f32)
    unsigned short* rbfA = (unsigned short*)(ws + 33554432); // 2 MB
    unsigned short* rbfB = (unsigned short*)(ws + 35651584); // 2 MB
    float* xc2 = (float*)(ws + 37748736);                    // 2 KB
    float* lossPart = (float*)(ws + 37752832);               // 100 KB (ITERS x 256)

    k_transpose<<<dim3(64, 32), 256, 0, stream>>>(W, Wt);
    k_prepx<<<512, 256, 0, stream>>>(x, cvec, xcbf, xc2);
    k_init<<<1024, 256, 0, stream>>>(r0, rbfA);
    // G = Wt @ Wt^T (W^T W), M=N=2048, K=4096 (1024 blocks, 4/CU)
    gemm64<64, 0><<<dim3(32, 32), 256, 0, stream>>>(Wt, D_SZ, Wt, D_SZ, D_SZ, Gbf, nullptr, H_SZ);
    // u = (x-c) @ W, M=512, N=2048, K=4096 (512 blocks, 2/CU)
    gemm64<32, 1><<<dim3(32, 16), 256, 0, stream>>>(xcbf, D_SZ, Wt, D_SZ, D_SZ, nullptr, u, H_SZ);

    void* args[] = {(void*)&r0, (void*)&rbfA, (void*)&rbfB, (void*)&Gbf, (void*)&u,
                    (void*)&bvec, (void*)&xc2, (void*)&lossPart, (void*)&out};
    hipLaunchCooperativeKernel((void*)k_persist, dim3(256), dim3(512), args, 0, stream);
}

// Round 8
// 2435.866 us; speedup vs baseline: 1.9324x; 1.9324x over previous
//
#include <hip/hip_runtime.h>
#include <cmath>

// Memory_76957224010242: 100-step Adam inference loop.
// G = W^T W, u = (x-c)@W once; per-iter s = r@G fused with Adam + loss.
// R8 (Config Z): loop GEMM = 1-wave blocks (64 thr), 32x32 tile, 1024 blocks
// (4/CU), ZERO barriers (single wave syncs via counted vmcnt), 4-buffer 3-deep
// global_load_lds pipeline. R7's cooperative grid.sync (~40us/iter) reverted.

#define B_SZ 512
#define H_SZ 2048
#define D_SZ 4096
#define ITERS 100

typedef __attribute__((ext_vector_type(8))) short short8;
typedef __attribute__((ext_vector_type(4))) float f32x4;

__device__ __forceinline__ unsigned short f2bf(float f) {
    unsigned u = __float_as_uint(f);
    u = (u + 0x7fffu + ((u >> 16) & 1u)) >> 16;  // RNE
    return (unsigned short)u;
}
__device__ __forceinline__ float bflo(unsigned mv) { return __uint_as_float(mv << 16); }
__device__ __forceinline__ float bfhi(unsigned mv) { return __uint_as_float(mv & 0xffff0000u); }

__device__ __forceinline__ void gload_lds16(const unsigned short* g, unsigned short* l) {
    __builtin_amdgcn_global_load_lds((const __attribute__((address_space(1))) void*)g,
                                     (__attribute__((address_space(3))) void*)l, 16, 0, 0);
}

// ---- W (D,H) f32 -> Wt (H,D) bf16 (transpose + cast) ----
__global__ __launch_bounds__(256) void k_transpose(const float* __restrict__ W,
                                                   unsigned short* __restrict__ Wt) {
    __shared__ unsigned short tile[64][72];
    const int d0 = blockIdx.x * 64, h0 = blockIdx.y * 64;
    const int t = threadIdx.x;
    const int lr = t >> 6, lc = t & 63;
#pragma unroll
    for (int rr = 0; rr < 16; ++rr) {
        const int dl = rr * 4 + lr;
        tile[dl][lc] = f2bf(W[(size_t)(d0 + dl) * H_SZ + h0 + lc]);
    }
    __syncthreads();
#pragma unroll
    for (int rr = 0; rr < 16; ++rr) {
        const int hl = rr * 4 + lr;
        Wt[(size_t)(h0 + hl) * D_SZ + d0 + lc] = tile[lc][hl];
    }
}

// ---- xc = (x - c) bf16, xc2[b] = sum_d (x-c)^2 ----
__global__ __launch_bounds__(256) void k_prepx(const float* __restrict__ x, const float* __restrict__ c,
                                               unsigned short* __restrict__ xcbf, float* __restrict__ xc2) {
    const int b = blockIdx.x, t = threadIdx.x;
    const float* xr = x + (size_t)b * D_SZ;
    unsigned short* orow = xcbf + (size_t)b * D_SZ;
    float acc = 0.f;
#pragma unroll
    for (int ch = 0; ch < 2; ++ch) {
        const int base = (ch * 256 + t) * 8;
        const float4 v0 = *(const float4*)(xr + base);
        const float4 v1 = *(const float4*)(xr + base + 4);
        const float4 c0 = *(const float4*)(c + base);
        const float4 c1 = *(const float4*)(c + base + 4);
        const float e0 = v0.x - c0.x, e1 = v0.y - c0.y, e2 = v0.z - c0.z, e3 = v0.w - c0.w;
        const float e4 = v1.x - c1.x, e5 = v1.y - c1.y, e6 = v1.z - c1.z, e7 = v1.w - c1.w;
        acc += e0 * e0 + e1 * e1 + e2 * e2 + e3 * e3 + e4 * e4 + e5 * e5 + e6 * e6 + e7 * e7;
        short8 ov;
        ov[0] = (short)f2bf(e0); ov[1] = (short)f2bf(e1); ov[2] = (short)f2bf(e2); ov[3] = (short)f2bf(e3);
        ov[4] = (short)f2bf(e4); ov[5] = (short)f2bf(e5); ov[6] = (short)f2bf(e6); ov[7] = (short)f2bf(e7);
        *(short8*)(orow + base) = ov;
    }
#pragma unroll
    for (int off = 32; off > 0; off >>= 1) acc += __shfl_down(acc, off);
    __shared__ float wred[4];
    if ((t & 63) == 0) wred[t >> 6] = acc;
    __syncthreads();
    if (t == 0) xc2[b] = wred[0] + wred[1] + wred[2] + wred[3];
}

// ---- r = r0; mv = 0; rbfA = bf16(r0) ----
__global__ __launch_bounds__(256) void k_init(const float* __restrict__ r0, float* __restrict__ r,
                                              unsigned* __restrict__ mv,
                                              unsigned short* __restrict__ rbfA) {
    const size_t i = (size_t)blockIdx.x * 256 + threadIdx.x;
#pragma unroll
    for (int k = 0; k < 4; ++k) {
        const size_t idx = i + (size_t)k * 262144;
        const float val = r0[idx];
        r[idx] = val; mv[idx] = 0u; rbfA[idx] = f2bf(val);
    }
}

// ---- one-time TM x 64 tile bf16 MFMA GEMM (EPI 0: bf16 store; EPI 1: f32 store) ----
template <int TM, int EPI>
__global__ __launch_bounds__(256) void gemm64(
        const unsigned short* __restrict__ A, int lda,
        const unsigned short* __restrict__ Bt, int ldb, int K,
        unsigned short* __restrict__ Cb, float* __restrict__ Cf, int ldc) {
    __shared__ alignas(16) unsigned short Al[2][TM * 64];
    __shared__ alignas(16) unsigned short Bl[2][64 * 64];
    const int t = threadIdx.x, w = t >> 6, lane = t & 63;
    const int m0 = blockIdx.y * TM, n0 = blockIdx.x * 64;
    constexpr int NJ = (TM == 64) ? 2 : 1;
    const int row_base = (TM == 64) ? (w >> 1) * 32 : 0;
    const int col_base = (TM == 64) ? (w & 1) * 32 : w * 16;

    f32x4 acc[2][NJ] = {};

    auto stage = [&](int buf, int k0) {
#pragma unroll
        for (int h = 0; h < 2; ++h) {
            const int c = h * 256 + t;
            const int row = c >> 3, g = c & 7;
            const int gl = g ^ (row & 7);
            gload_lds16(Bt + (size_t)(n0 + row) * ldb + k0 + gl * 8, &Bl[buf][(h * 256 + w * 64) * 8]);
        }
        if constexpr (TM == 64) {
#pragma unroll
            for (int h = 0; h < 2; ++h) {
                const int c = h * 256 + t;
                const int row = c >> 3, g = c & 7;
                const int gl = g ^ (row & 7);
                gload_lds16(A + (size_t)(m0 + row) * lda + k0 + gl * 8, &Al[buf][(h * 256 + w * 64) * 8]);
            }
        } else {
            const int row = t >> 3, g = t & 7;
            const int gl = g ^ (row & 7);
            gload_lds16(A + (size_t)(m0 + row) * lda + k0 + gl * 8, &Al[buf][(w * 64) * 8]);
        }
    };

    stage(0, 0);
    const int nK = K >> 6;
    for (int kt = 0; kt < nK; ++kt) {
        __syncthreads();
        const int cur = kt & 1;
        if (kt + 1 < nK) stage(cur ^ 1, (kt + 1) << 6);
        const unsigned short* a_base = Al[cur];
        const unsigned short* b_base = Bl[cur];
#pragma unroll
        for (int kh = 0; kh < 2; ++kh) {
            short8 av[2], bv[NJ];
#pragma unroll
            for (int i = 0; i < 2; ++i) {
                const int row = row_base + i * 16 + (lane & 15);
                const int g = (kh * 4 + (lane >> 4)) ^ (row & 7);
                av[i] = *(const short8*)(a_base + row * 64 + g * 8);
            }
#pragma unroll
            for (int j = 0; j < NJ; ++j) {
                const int row = col_base + j * 16 + (lane & 15);
                const int g = (kh * 4 + (lane >> 4)) ^ (row & 7);
                bv[j] = *(const short8*)(b_base + row * 64 + g * 8);
            }
#pragma unroll
            for (int i = 0; i < 2; ++i)
#pragma unroll
                for (int j = 0; j < NJ; ++j)
                    acc[i][j] = __builtin_amdgcn_mfma_f32_16x16x32_bf16(av[i], bv[j], acc[i][j], 0, 0, 0);
        }
    }

#pragma unroll
    for (int i = 0; i < 2; ++i)
#pragma unroll
        for (int j = 0; j < NJ; ++j) {
            const int col = n0 + col_base + j * 16 + (lane & 15);
            const int row0 = m0 + row_base + i * 16 + ((lane >> 4) << 2);
#pragma unroll
            for (int q = 0; q < 4; ++q) {
                if constexpr (EPI == 0) Cb[(size_t)(row0 + q) * ldc + col] = f2bf(acc[i][j][q]);
                else Cf[(size_t)(row0 + q) * ldc + col] = acc[i][j][q];
            }
        }
}

// ---- loop kernel (Config Z): one wave per block, 32x32 C-tile, no barriers.
// s = r@G (M=512,N=2048,K=2048) fused with Adam + loss.
__global__ __launch_bounds__(64) void gemm_z(
        const unsigned short* __restrict__ Ain,   // bf16 r in (B_SZ x H)
        const unsigned short* __restrict__ G,     // bf16 G (H x H)
        const float* __restrict__ rin,
        float* __restrict__ rout,
        unsigned* __restrict__ mv,
        const float* __restrict__ ubuf,
        const float* __restrict__ bvec,
        unsigned short* __restrict__ rbf_out,     // null on last iter
        float* __restrict__ lossPart,
        float inv1, float inv2) {
    __shared__ alignas(16) unsigned short Al[4][32 * 64];
    __shared__ alignas(16) unsigned short Bl[4][32 * 64];
    const int lane = threadIdx.x;
    const int m0 = blockIdx.y * 32, n0 = blockIdx.x * 32;
    const int bid = blockIdx.y * 64 + blockIdx.x;
    const int rlo = lane & 15, hi = lane >> 4;

    // ---- epilogue-state prefetch (issued first; oldest in the vmcnt FIFO) ----
    const int col0 = n0 + rlo;
    const int rowb = m0 + (hi << 2);
    float pre_r[16], pre_u[16], pre_b[2];
    unsigned pre_mv[16];
    pre_b[0] = bvec[col0]; pre_b[1] = bvec[col0 + 16];
#pragma unroll
    for (int i = 0; i < 2; ++i)
#pragma unroll
        for (int j = 0; j < 2; ++j)
#pragma unroll
            for (int q = 0; q < 4; ++q) {
                const size_t idx = (size_t)(rowb + i * 16 + q) * H_SZ + col0 + j * 16;
                const int e = (i * 2 + j) * 4 + q;
                pre_r[e] = rin[idx]; pre_u[e] = ubuf[idx]; pre_mv[e] = mv[idx];
            }
    __builtin_amdgcn_sched_barrier(0);  // keep prefetch ahead of staging in the FIFO

    // ---- staging: 8 gload_lds16 per stage; source XOR-swizzled (Guideline 21) ----
    const int srow = lane >> 3;                // 0..7
    const int sg = (lane & 7) ^ (srow & 7);    // per-lane constant
    const unsigned short* abase = Ain + (size_t)(m0 + srow) * H_SZ + sg * 8;
    const unsigned short* gbase = G + (size_t)(n0 + srow) * H_SZ + sg * 8;
    auto stage = [&](int buf, int kc) {
        const int k0 = kc * 64;
#pragma unroll
        for (int h = 0; h < 4; ++h) {
            gload_lds16(abase + (size_t)(h * 8) * H_SZ + k0, &Al[buf][h * 512 + lane * 8]);
            gload_lds16(gbase + (size_t)(h * 8) * H_SZ + k0, &Bl[buf][h * 512 + lane * 8]);
        }
    };
    stage(0, 0); stage(1, 1); stage(2, 2);

    f32x4 acc[2][2] = {};
    for (int kt = 0; kt < 32; ++kt) {
        // counted vmcnt: 3 stages (24 loads) in flight; oldest stage done at <=16.
        if (kt < 30)       asm volatile("s_waitcnt vmcnt(16)" ::: "memory");
        else if (kt == 30) asm volatile("s_waitcnt vmcnt(8)" ::: "memory");
        else               asm volatile("s_waitcnt vmcnt(0)" ::: "memory");
        if (kt + 3 < 32) stage((kt + 3) & 3, kt + 3);
        const unsigned short* a_base = Al[kt & 3];
        const unsigned short* b_base = Bl[kt & 3];
#pragma unroll
        for (int kh = 0; kh < 2; ++kh) {
            short8 av[2], bv[2];
#pragma unroll
            for (int i = 0; i < 2; ++i) {
                const int row = i * 16 + rlo;
                av[i] = *(const short8*)(a_base + row * 64 + ((kh * 4 + hi) ^ (row & 7)) * 8);
            }
#pragma unroll
            for (int j = 0; j < 2; ++j) {
                const int row = j * 16 + rlo;
                bv[j] = *(const short8*)(b_base + row * 64 + ((kh * 4 + hi) ^ (row & 7)) * 8);
            }
#pragma unroll
            for (int i = 0; i < 2; ++i)
#pragma unroll
                for (int j = 0; j < 2; ++j)
                    acc[i][j] = __builtin_amdgcn_mfma_f32_16x16x32_bf16(av[i], bv[j], acc[i][j], 0, 0, 0);
        }
    }

    // ---- fused Adam + loss (state already in registers) ----
    float lpart = 0.f;
#pragma unroll
    for (int i = 0; i < 2; ++i)
#pragma unroll
        for (int j = 0; j < 2; ++j)
#pragma unroll
            for (int q = 0; q < 4; ++q) {
                const size_t idx = (size_t)(rowb + i * 16 + q) * H_SZ + col0 + j * 16;
                const int e = (i * 2 + j) * 4 + q;
                const float s = acc[i][j][q];
                const float rold = pre_r[e];
                const float ue = pre_u[e];
                const float g = (2.0f / B_SZ) * (rold - pre_b[j] - ue + s);
                lpart += (rold - pre_b[j]) * (rold - pre_b[j]) + rold * (s - 2.0f * ue);
                const float m1 = 0.9f * bflo(pre_mv[e]) + 0.1f * g;
                const float v1 = 0.999f * bfhi(pre_mv[e]) + 0.001f * (g * g);
                mv[idx] = (unsigned)f2bf(m1) | ((unsigned)f2bf(v1) << 16);
                const float rn = rold - 0.01f * (m1 * inv1) / (sqrtf(v1 * inv2) + 1e-8f);
                rout[idx] = rn;
                if (rbf_out) rbf_out[idx] = f2bf(rn);
            }
#pragma unroll
    for (int off = 32; off > 0; off >>= 1) lpart += __shfl_down(lpart, off);
    if (lane == 0) lossPart[bid] = lpart;
}

// ---- losses[t] = (sum of 1024 lossPart + sum_b xc2) / B ----
__global__ __launch_bounds__(256) void k_finalize(const float* __restrict__ lossPart,
                                                  const float* __restrict__ xc2, float* __restrict__ out) {
    const int it = blockIdx.x, t = threadIdx.x;
    const float* lp = lossPart + (size_t)it * 1024;
    float p = lp[t] + lp[t + 256] + lp[t + 512] + lp[t + 768] + xc2[t] + xc2[t + 256];
#pragma unroll
    for (int off = 32; off > 0; off >>= 1) p += __shfl_down(p, off);
    __shared__ float wred[4];
    if ((t & 63) == 0) wred[t >> 6] = p;
    __syncthreads();
    if (t == 0) out[(size_t)B_SZ * H_SZ + it] = (wred[0] + wred[1] + wred[2] + wred[3]) * (1.0f / B_SZ);
}

extern "C" void kernel_launch(void* const* d_in, const int* in_sizes, int n_in,
                              void* d_out, int out_size, void* d_ws, size_t ws_size,
                              hipStream_t stream) {
    const float* x = (const float*)d_in[0];
    const float* W = (const float*)d_in[1];
    const float* cvec = (const float*)d_in[2];
    const float* bvec = (const float*)d_in[3];
    const float* r0 = (const float*)d_in[4];
    float* out = (float*)d_out;
    char* ws = (char*)d_ws;

    unsigned short* Wt = (unsigned short*)(ws);              // 16 MB   (H x D bf16)
    unsigned short* Gbf = (unsigned short*)(ws + 16777216);  // 8 MB    (H x H bf16)
    unsigned short* xcbf = (unsigned short*)(ws + 25165824); // 4 MB    (B x D bf16)
    float* u = (float*)(ws + 29360128);                      // 4 MB    (B x H f32)
    float* r = (float*)(ws + 33554432);                      // 4 MB
    unsigned* mv = (unsigned*)(ws + 37748736);               // 4 MB    (bf16 m | bf16 v packed)
    unsigned short* rbfA = (unsigned short*)(ws + 41943040); // 2 MB
    unsigned short* rbfB = (unsigned short*)(ws + 44040192); // 2 MB
    float* xc2 = (float*)(ws + 46137344);                    // 2 KB
    float* lossPart = (float*)(ws + 46139392);               // 400 KB (ITERS x 1024)

    k_transpose<<<dim3(64, 32), 256, 0, stream>>>(W, Wt);
    k_prepx<<<512, 256, 0, stream>>>(x, cvec, xcbf, xc2);
    k_init<<<1024, 256, 0, stream>>>(r0, r, mv, rbfA);
    // G = Wt @ Wt^T (W^T W), M=N=2048, K=4096 (1024 blocks, 4/CU)
    gemm64<64, 0><<<dim3(32, 32), 256, 0, stream>>>(Wt, D_SZ, Wt, D_SZ, D_SZ, Gbf, nullptr, H_SZ);
    // u = (x-c) @ W, M=512, N=2048, K=4096 (512 blocks, 2/CU)
    gemm64<32, 1><<<dim3(32, 16), 256, 0, stream>>>(xcbf, D_SZ, Wt, D_SZ, D_SZ, nullptr, u, H_SZ);

    for (int it = 0; it < ITERS; ++it) {
        const float inv1 = (float)(1.0 / (1.0 - std::pow(0.9, (double)(it + 1))));
        const float inv2 = (float)(1.0 / (1.0 - std::pow(0.999, (double)(it + 1))));
        const unsigned short* rin_bf = (it & 1) ? rbfB : rbfA;
        unsigned short* rout_bf = (it + 1 < ITERS) ? ((it & 1) ? rbfA : rbfB) : nullptr;
        float* rout_f = (it + 1 < ITERS) ? r : out;  // last iter writes f32 r into d_out
        gemm_z<<<dim3(64, 16), 64, 0, stream>>>(rin_bf, Gbf, r, rout_f, mv, u, bvec, rout_bf,
                                                lossPart + (size_t)it * 1024, inv1, inv2);
    }
    k_finalize<<<ITERS, 256, 0, stream>>>(lossPart, xc2, out);
}

// Round 9
// 2297.800 us; speedup vs baseline: 2.0485x; 1.0601x over previous
//
#include <hip/hip_runtime.h>
#include <cmath>

// Memory_76957224010242: 100-step Adam inference loop.
// G = W^T W, u = (x-c)@W once; per-iter s = r@G fused with Adam + loss.
// R9: loop GEMM = 64x64 tile, 512 threads (8 waves), 256 blocks (1/CU,
// 2 waves/SIMD). Staged bytes 192->128 MB/iter; XCD-aware n-mapping keeps each
// XCD's 1 MB G-panel L2-resident across all 100 iters.

#define B_SZ 512
#define H_SZ 2048
#define D_SZ 4096
#define ITERS 100

typedef __attribute__((ext_vector_type(8))) short short8;
typedef __attribute__((ext_vector_type(4))) float f32x4;

__device__ __forceinline__ unsigned short f2bf(float f) {
    unsigned u = __float_as_uint(f);
    u = (u + 0x7fffu + ((u >> 16) & 1u)) >> 16;  // RNE
    return (unsigned short)u;
}
__device__ __forceinline__ float bflo(unsigned mv) { return __uint_as_float(mv << 16); }
__device__ __forceinline__ float bfhi(unsigned mv) { return __uint_as_float(mv & 0xffff0000u); }

__device__ __forceinline__ void gload_lds16(const unsigned short* g, unsigned short* l) {
    __builtin_amdgcn_global_load_lds((const __attribute__((address_space(1))) void*)g,
                                     (__attribute__((address_space(3))) void*)l, 16, 0, 0);
}

// ---- W (D,H) f32 -> Wt (H,D) bf16 (transpose + cast) ----
__global__ __launch_bounds__(256) void k_transpose(const float* __restrict__ W,
                                                   unsigned short* __restrict__ Wt) {
    __shared__ unsigned short tile[64][72];
    const int d0 = blockIdx.x * 64, h0 = blockIdx.y * 64;
    const int t = threadIdx.x;
    const int lr = t >> 6, lc = t & 63;
#pragma unroll
    for (int rr = 0; rr < 16; ++rr) {
        const int dl = rr * 4 + lr;
        tile[dl][lc] = f2bf(W[(size_t)(d0 + dl) * H_SZ + h0 + lc]);
    }
    __syncthreads();
#pragma unroll
    for (int rr = 0; rr < 16; ++rr) {
        const int hl = rr * 4 + lr;
        Wt[(size_t)(h0 + hl) * D_SZ + d0 + lc] = tile[lc][hl];
    }
}

// ---- xc = (x - c) bf16, xc2[b] = sum_d (x-c)^2 ----
__global__ __launch_bounds__(256) void k_prepx(const float* __restrict__ x, const float* __restrict__ c,
                                               unsigned short* __restrict__ xcbf, float* __restrict__ xc2) {
    const int b = blockIdx.x, t = threadIdx.x;
    const float* xr = x + (size_t)b * D_SZ;
    unsigned short* orow = xcbf + (size_t)b * D_SZ;
    float acc = 0.f;
#pragma unroll
    for (int ch = 0; ch < 2; ++ch) {
        const int base = (ch * 256 + t) * 8;
        const float4 v0 = *(const float4*)(xr + base);
        const float4 v1 = *(const float4*)(xr + base + 4);
        const float4 c0 = *(const float4*)(c + base);
        const float4 c1 = *(const float4*)(c + base + 4);
        const float e0 = v0.x - c0.x, e1 = v0.y - c0.y, e2 = v0.z - c0.z, e3 = v0.w - c0.w;
        const float e4 = v1.x - c1.x, e5 = v1.y - c1.y, e6 = v1.z - c1.z, e7 = v1.w - c1.w;
        acc += e0 * e0 + e1 * e1 + e2 * e2 + e3 * e3 + e4 * e4 + e5 * e5 + e6 * e6 + e7 * e7;
        short8 ov;
        ov[0] = (short)f2bf(e0); ov[1] = (short)f2bf(e1); ov[2] = (short)f2bf(e2); ov[3] = (short)f2bf(e3);
        ov[4] = (short)f2bf(e4); ov[5] = (short)f2bf(e5); ov[6] = (short)f2bf(e6); ov[7] = (short)f2bf(e7);
        *(short8*)(orow + base) = ov;
    }
#pragma unroll
    for (int off = 32; off > 0; off >>= 1) acc += __shfl_down(acc, off);
    __shared__ float wred[4];
    if ((t & 63) == 0) wred[t >> 6] = acc;
    __syncthreads();
    if (t == 0) xc2[b] = wred[0] + wred[1] + wred[2] + wred[3];
}

// ---- r = r0; mv = 0; rbfA = bf16(r0) ----
__global__ __launch_bounds__(256) void k_init(const float* __restrict__ r0, float* __restrict__ r,
                                              unsigned* __restrict__ mv,
                                              unsigned short* __restrict__ rbfA) {
    const size_t i = (size_t)blockIdx.x * 256 + threadIdx.x;
#pragma unroll
    for (int k = 0; k < 4; ++k) {
        const size_t idx = i + (size_t)k * 262144;
        const float val = r0[idx];
        r[idx] = val; mv[idx] = 0u; rbfA[idx] = f2bf(val);
    }
}

// ---- one-time TM x 64 tile bf16 MFMA GEMM (EPI 0: bf16 store; EPI 1: f32 store) ----
template <int TM, int EPI>
__global__ __launch_bounds__(256) void gemm64(
        const unsigned short* __restrict__ A, int lda,
        const unsigned short* __restrict__ Bt, int ldb, int K,
        unsigned short* __restrict__ Cb, float* __restrict__ Cf, int ldc) {
    __shared__ alignas(16) unsigned short Al[2][TM * 64];
    __shared__ alignas(16) unsigned short Bl[2][64 * 64];
    const int t = threadIdx.x, w = t >> 6, lane = t & 63;
    const int m0 = blockIdx.y * TM, n0 = blockIdx.x * 64;
    constexpr int NJ = (TM == 64) ? 2 : 1;
    const int row_base = (TM == 64) ? (w >> 1) * 32 : 0;
    const int col_base = (TM == 64) ? (w & 1) * 32 : w * 16;

    f32x4 acc[2][NJ] = {};

    auto stage = [&](int buf, int k0) {
#pragma unroll
        for (int h = 0; h < 2; ++h) {
            const int c = h * 256 + t;
            const int row = c >> 3, g = c & 7;
            const int gl = g ^ (row & 7);
            gload_lds16(Bt + (size_t)(n0 + row) * ldb + k0 + gl * 8, &Bl[buf][(h * 256 + w * 64) * 8]);
        }
        if constexpr (TM == 64) {
#pragma unroll
            for (int h = 0; h < 2; ++h) {
                const int c = h * 256 + t;
                const int row = c >> 3, g = c & 7;
                const int gl = g ^ (row & 7);
                gload_lds16(A + (size_t)(m0 + row) * lda + k0 + gl * 8, &Al[buf][(h * 256 + w * 64) * 8]);
            }
        } else {
            const int row = t >> 3, g = t & 7;
            const int gl = g ^ (row & 7);
            gload_lds16(A + (size_t)(m0 + row) * lda + k0 + gl * 8, &Al[buf][(w * 64) * 8]);
        }
    };

    stage(0, 0);
    const int nK = K >> 6;
    for (int kt = 0; kt < nK; ++kt) {
        __syncthreads();
        const int cur = kt & 1;
        if (kt + 1 < nK) stage(cur ^ 1, (kt + 1) << 6);
        const unsigned short* a_base = Al[cur];
        const unsigned short* b_base = Bl[cur];
#pragma unroll
        for (int kh = 0; kh < 2; ++kh) {
            short8 av[2], bv[NJ];
#pragma unroll
            for (int i = 0; i < 2; ++i) {
                const int row = row_base + i * 16 + (lane & 15);
                const int g = (kh * 4 + (lane >> 4)) ^ (row & 7);
                av[i] = *(const short8*)(a_base + row * 64 + g * 8);
            }
#pragma unroll
            for (int j = 0; j < NJ; ++j) {
                const int row = col_base + j * 16 + (lane & 15);
                const int g = (kh * 4 + (lane >> 4)) ^ (row & 7);
                bv[j] = *(const short8*)(b_base + row * 64 + g * 8);
            }
#pragma unroll
            for (int i = 0; i < 2; ++i)
#pragma unroll
                for (int j = 0; j < NJ; ++j)
                    acc[i][j] = __builtin_amdgcn_mfma_f32_16x16x32_bf16(av[i], bv[j], acc[i][j], 0, 0, 0);
        }
    }

#pragma unroll
    for (int i = 0; i < 2; ++i)
#pragma unroll
        for (int j = 0; j < NJ; ++j) {
            const int col = n0 + col_base + j * 16 + (lane & 15);
            const int row0 = m0 + row_base + i * 16 + ((lane >> 4) << 2);
#pragma unroll
            for (int q = 0; q < 4; ++q) {
                if constexpr (EPI == 0) Cb[(size_t)(row0 + q) * ldc + col] = f2bf(acc[i][j][q]);
                else Cf[(size_t)(row0 + q) * ldc + col] = acc[i][j][q];
            }
        }
}

// ---- loop kernel: 64x64 tile, 8 waves (512 thr), 256 blocks (1/CU).
// s = r@G (M=512,N=2048,K=2048) fused with Adam + loss.
// n-mapping: n_tile = (bid&7)*4 + ((bid>>3)&3) -> each XCD re-reads a stable
// 1 MB G panel (L2-resident); m_tile = bid>>5.
__global__ __launch_bounds__(512) void gemm_q(
        const unsigned short* __restrict__ Ain,   // bf16 r in (B_SZ x H)
        const unsigned short* __restrict__ G,     // bf16 G (H x H)
        const float* __restrict__ rin,
        float* __restrict__ rout,
        unsigned* __restrict__ mv,
        const float* __restrict__ ubuf,
        const float* __restrict__ bvec,
        unsigned short* __restrict__ rbf_out,     // null on last iter
        float* __restrict__ lossPart,
        float inv1, float inv2) {
    __shared__ alignas(16) unsigned short Al[2][64 * 64];
    __shared__ alignas(16) unsigned short Bl[2][64 * 64];
    const int t = threadIdx.x, w = t >> 6, lane = t & 63;
    const int bid = blockIdx.x;
    const int m0 = (bid >> 5) * 64;
    const int n0 = ((bid & 7) * 4 + ((bid >> 3) & 3)) * 64;
    const int row_base = (w >> 2) * 32;   // 2 wave-rows
    const int col_base = (w & 3) * 16;    // 4 wave-cols
    const int rlo = lane & 15, hi = lane >> 4;

    // ---- epilogue-state prefetch (completes under the K-loop) ----
    const int col0 = n0 + col_base + rlo;
    const int rowb = m0 + row_base + (hi << 2);
    float pre_r[8], pre_u[8];
    unsigned pre_mv[8];
    const float pre_b = bvec[col0];
#pragma unroll
    for (int i = 0; i < 2; ++i)
#pragma unroll
        for (int q = 0; q < 4; ++q) {
            const size_t idx = (size_t)(rowb + i * 16 + q) * H_SZ + col0;
            const int e = i * 4 + q;
            pre_r[e] = rin[idx]; pre_u[e] = ubuf[idx]; pre_mv[e] = mv[idx];
        }
    __builtin_amdgcn_sched_barrier(0);

    // ---- staging: 1 A-load + 1 G-load per thread per stage (8 KB each) ----
    const int srow = t >> 3;                 // 0..63
    const int sg = (t & 7) ^ (srow & 7);     // source-side XOR swizzle (Guideline 21)
    const unsigned short* abase = Ain + (size_t)(m0 + srow) * H_SZ + sg * 8;
    const unsigned short* gbase = G + (size_t)(n0 + srow) * H_SZ + sg * 8;
    auto stage = [&](int buf, int kt) {
        gload_lds16(abase + kt * 64, &Al[buf][t * 8]);
        gload_lds16(gbase + kt * 64, &Bl[buf][t * 8]);
    };

    stage(0, 0);
    f32x4 acc[2] = {};
    for (int kt = 0; kt < 32; ++kt) {
        __syncthreads();
        const int cur = kt & 1;
        if (kt + 1 < 32) stage(cur ^ 1, kt + 1);
        const unsigned short* a_base = Al[cur];
        const unsigned short* b_base = Bl[cur];
#pragma unroll
        for (int kh = 0; kh < 2; ++kh) {
            short8 av[2], bv;
#pragma unroll
            for (int i = 0; i < 2; ++i) {
                const int row = row_base + i * 16 + rlo;
                av[i] = *(const short8*)(a_base + row * 64 + ((kh * 4 + hi) ^ (row & 7)) * 8);
            }
            {
                const int row = col_base + rlo;
                bv = *(const short8*)(b_base + row * 64 + ((kh * 4 + hi) ^ (row & 7)) * 8);
            }
#pragma unroll
            for (int i = 0; i < 2; ++i)
                acc[i] = __builtin_amdgcn_mfma_f32_16x16x32_bf16(av[i], bv, acc[i], 0, 0, 0);
        }
    }

    // ---- fused Adam + loss (state already in registers) ----
    float lpart = 0.f;
#pragma unroll
    for (int i = 0; i < 2; ++i)
#pragma unroll
        for (int q = 0; q < 4; ++q) {
            const size_t idx = (size_t)(rowb + i * 16 + q) * H_SZ + col0;
            const int e = i * 4 + q;
            const float s = acc[i][q];
            const float rold = pre_r[e];
            const float ue = pre_u[e];
            const float g = (2.0f / B_SZ) * (rold - pre_b - ue + s);
            lpart += (rold - pre_b) * (rold - pre_b) + rold * (s - 2.0f * ue);
            const float m1 = 0.9f * bflo(pre_mv[e]) + 0.1f * g;
            const float v1 = 0.999f * bfhi(pre_mv[e]) + 0.001f * (g * g);
            mv[idx] = (unsigned)f2bf(m1) | ((unsigned)f2bf(v1) << 16);
            const float rn = rold - 0.01f * (m1 * inv1) / (sqrtf(v1 * inv2) + 1e-8f);
            rout[idx] = rn;
            if (rbf_out) rbf_out[idx] = f2bf(rn);
        }
#pragma unroll
    for (int off = 32; off > 0; off >>= 1) lpart += __shfl_down(lpart, off);
    __shared__ float wred[8];
    if (lane == 0) wred[w] = lpart;
    __syncthreads();
    if (t == 0) {
        float sum = 0.f;
#pragma unroll
        for (int k = 0; k < 8; ++k) sum += wred[k];
        lossPart[bid] = sum;
    }
}

// ---- losses[t] = (sum of 256 lossPart + sum_b xc2) / B ----
__global__ __launch_bounds__(256) void k_finalize(const float* __restrict__ lossPart,
                                                  const float* __restrict__ xc2, float* __restrict__ out) {
    const int it = blockIdx.x, t = threadIdx.x;
    float p = lossPart[it * 256 + t] + xc2[t] + xc2[t + 256];
#pragma unroll
    for (int off = 32; off > 0; off >>= 1) p += __shfl_down(p, off);
    __shared__ float wred[4];
    if ((t & 63) == 0) wred[t >> 6] = p;
    __syncthreads();
    if (t == 0) out[(size_t)B_SZ * H_SZ + it] = (wred[0] + wred[1] + wred[2] + wred[3]) * (1.0f / B_SZ);
}

extern "C" void kernel_launch(void* const* d_in, const int* in_sizes, int n_in,
                              void* d_out, int out_size, void* d_ws, size_t ws_size,
                              hipStream_t stream) {
    const float* x = (const float*)d_in[0];
    const float* W = (const float*)d_in[1];
    const float* cvec = (const float*)d_in[2];
    const float* bvec = (const float*)d_in[3];
    const float* r0 = (const float*)d_in[4];
    float* out = (float*)d_out;
    char* ws = (char*)d_ws;

    unsigned short* Wt = (unsigned short*)(ws);              // 16 MB   (H x D bf16)
    unsigned short* Gbf = (unsigned short*)(ws + 16777216);  // 8 MB    (H x H bf16)
    unsigned short* xcbf = (unsigned short*)(ws + 25165824); // 4 MB    (B x D bf16)
    float* u = (float*)(ws + 29360128);                      // 4 MB    (B x H f32)
    float* r = (float*)(ws + 33554432);                      // 4 MB
    unsigned* mv = (unsigned*)(ws + 37748736);               // 4 MB    (bf16 m | bf16 v packed)
    unsigned short* rbfA = (unsigned short*)(ws + 41943040); // 2 MB
    unsigned short* rbfB = (unsigned short*)(ws + 44040192); // 2 MB
    float* xc2 = (float*)(ws + 46137344);                    // 2 KB
    float* lossPart = (float*)(ws + 46139392);               // 100 KB (ITERS x 256)

    k_transpose<<<dim3(64, 32), 256, 0, stream>>>(W, Wt);
    k_prepx<<<512, 256, 0, stream>>>(x, cvec, xcbf, xc2);
    k_init<<<1024, 256, 0, stream>>>(r0, r, mv, rbfA);
    // G = Wt @ Wt^T (W^T W), M=N=2048, K=4096 (1024 blocks, 4/CU)
    gemm64<64, 0><<<dim3(32, 32), 256, 0, stream>>>(Wt, D_SZ, Wt, D_SZ, D_SZ, Gbf, nullptr, H_SZ);
    // u = (x-c) @ W, M=512, N=2048, K=4096 (512 blocks, 2/CU)
    gemm64<32, 1><<<dim3(32, 16), 256, 0, stream>>>(xcbf, D_SZ, Wt, D_SZ, D_SZ, nullptr, u, H_SZ);

    for (int it = 0; it < ITERS; ++it) {
        const float inv1 = (float)(1.0 / (1.0 - std::pow(0.9, (double)(it + 1))));
        const float inv2 = (float)(1.0 / (1.0 - std::pow(0.999, (double)(it + 1))));
        const unsigned short* rin_bf = (it & 1) ? rbfB : rbfA;
        unsigned short* rout_bf = (it + 1 < ITERS) ? ((it & 1) ? rbfA : rbfB) : nullptr;
        float* rout_f = (it + 1 < ITERS) ? r : out;  // last iter writes f32 r into d_out
        gemm_q<<<256, 512, 0, stream>>>(rin_bf, Gbf, r, rout_f, mv, u, bvec, rout_bf,
                                        lossPart + (size_t)it * 256, inv1, inv2);
    }
    k_finalize<<<ITERS, 256, 0, stream>>>(lossPart, xc2, out);
}